// Round 18
// baseline (42.387 us; speedup 1.0000x reference)
//
#include <hip/hip_runtime.h>

typedef __bf16 v8bf __attribute__((ext_vector_type(8)));
typedef float f32x4 __attribute__((ext_vector_type(4)));
typedef unsigned int u32;

#define C_IN 256
#define HW   64
#define OHW  63
#define NOC  128
#define BUFSZ 21120

// Wf: [kp(4)][khkw(4)][cblk(32)][oc(128)][j(8)] bf16, 1 MiB. Coalesced.
__global__ void wprep(const float* __restrict__ w, __bf16* __restrict__ Wf) {
  int f = blockIdx.x;                 // 512 filters
  int c = threadIdx.x;                // 256 channels
  f32x4 v = *(const f32x4*)(w + (size_t)f * 1024 + c * 4);  // 4 khkw taps
  int oc = f >> 2, kp = f & 3;
#pragma unroll
  for (int khkw = 0; khkw < 4; ++khkw)
    Wf[(((size_t)(kp * 4 + khkw) * 32 + (c >> 3)) * 128 + oc) * 8 + (c & 7)] =
        (__bf16)v[khkw];
}

// R17 + 3-bank register staging: concurrent prologue loads (1 HBM round-trip
// instead of ~3) and 2-slot delivery lead in the loop (W never waits).
// Block: n x 4 out rows x 128 oc, 1024 thr (16 waves, 4/SIMD), XCD-swizzled
// 1-D grid. 4-buffer LDS pipeline, barrier every 2 chunks; setprio; 2-pass
// LDS-transposed epilogue.
// Bank schedule (x chunk -> reg bank): 0->b0 1->b1 2->b2 3->b0 4->b1 5->b2
// 6->b0 7->b1; L(q+4) at slot q uses the bank freed at slot q-1; every LDS
// buf write/read pair is separated by >=1 barrier (table re-verified).
__global__ __launch_bounds__(1024, 4) void robin_main(
    const float* __restrict__ x, const __bf16* __restrict__ Wf,
    const float* __restrict__ bias, float* __restrict__ out) {
  __shared__ __align__(16) char smem[4 * BUFSZ];   // 84480 loop / 69632 epi

  const int tid  = threadIdx.x;
  const int lane = tid & 63;
  const int wid  = tid >> 6;
  const int bid  = blockIdx.x;       // 256, swizzled decode below
  const int hb   = (bid >> 3) & 15;  // strip: same-XCD blocks share n-column
  const int n    = ((bid & 7) << 1) | (bid >> 7);
  const int h0   = hb * 4;

  const int ocg  = wid >> 2;         // 0..3 -> 32 oc each
  const int kp   = wid & 3;          // parity class
  const int ph   = kp >> 1, pw = kp & 1;
  const int lcol = lane & 15;        // pixel col (B) / oc row (A)
  const int lg   = lane >> 4;        // k-octet group

  // zero-fill wpair=32 pad rows (wcol 64/65), all 4 buffers
  if (tid < 160) {
    int g  = tid & 7;
    int t2 = tid >> 3;
    int dy = t2 % 5, bi = t2 / 5;    // bi 0..3
    f32x4 z = {0.f, 0.f, 0.f, 0.f};
    *(f32x4*)(smem + bi * BUFSZ + (dy * 33 + 32) * 128 + g * 16) = z;
  }

  // chunk-invariant B-frag base offsets (r -> +8448, hh -> +2048)
  int boff[4];
#pragma unroll
  for (int khkw = 0; khkw < 4; ++khkw) {
    int kh = khkw >> 1, kw = khkw & 1;
    int dy0  = ph + kh;
    int wcol = 2 * lcol + pw + kw;
    int wp_  = wcol >> 1;
    boff[khkw] = ((dy0 * 33 + wp_) * 128 + (wcol & 1) * 64 + lg * 16) ^
                 ((wp_ & 7) << 4);
  }

  f32x4 acc[2][4];
#pragma unroll
  for (int m = 0; m < 2; ++m)
#pragma unroll
    for (int f = 0; f < 4; ++f) acc[m][f] = (f32x4){0.f, 0.f, 0.f, 0.f};

  const float* xbase = x + (size_t)n * C_IN * HW * HW;

  // staging partition (R14): thread = c-pair (2*wid, 2*wid+1) at w=lane.
  const int wp_s  = lane >> 1;
  const int par_s = lane & 1;
  const int bo_s  = ((wp_s * 128) + par_s * 64 + wid * 4) ^ ((wp_s & 7) << 4);
  float xlo0[5], xhi0[5], xlo1[5], xhi1[5], xlo2[5], xhi2[5];
  v8bf  a_reg[4][2];

#define A_LOAD(QQ)                                                             \
  {                                                                            \
    _Pragma("unroll") for (int khkw = 0; khkw < 4; ++khkw) {                   \
      const __bf16* wp =                                                       \
          Wf + (((size_t)(kp * 4 + khkw) * 32 + (QQ) * 4 + lg) * 128 +        \
                ocg * 32 + lcol) * 8;                                          \
      a_reg[khkw][0] = *(const v8bf*)wp;                                       \
      a_reg[khkw][1] = *(const v8bf*)(wp + 128);                               \
    }                                                                          \
  }

  // 10 coalesced dword loads: c-planes (2*wid, 2*wid+1), rows h0..h0+4
#define LOADQ(QQ, XLO, XHI)                                                    \
  {                                                                            \
    const float* bp =                                                          \
        xbase + ((size_t)((QQ) * 32 + 2 * wid)) * 4096 + h0 * 64 + lane;       \
    _Pragma("unroll") for (int k = 0; k < 4; ++k) {                            \
      XLO[k] = bp[k * 64];                                                     \
      XHI[k] = bp[4096 + k * 64];                                              \
    }                                                                          \
    if (h0 + 4 < HW) {                                                         \
      XLO[4] = bp[4 * 64];                                                     \
      XHI[4] = bp[4096 + 4 * 64];                                              \
    } else {                                                                   \
      XLO[4] = 0.f;                                                            \
      XHI[4] = 0.f;                                                            \
    }                                                                          \
  }

  // 5 ds_write_b32 per thread into buf (QQ)&3
#define WRITEQ(QQ, XLO, XHI)                                                   \
  {                                                                            \
    char* xd = smem + ((QQ) & 3) * BUFSZ;                                      \
    _Pragma("unroll") for (int k = 0; k < 5; ++k) {                            \
      unsigned short a_ = __builtin_bit_cast(unsigned short, (__bf16)XLO[k]);  \
      unsigned short b_ = __builtin_bit_cast(unsigned short, (__bf16)XHI[k]);  \
      *(u32*)(xd + bo_s + k * 4224) = (u32)a_ | ((u32)b_ << 16);               \
    }                                                                          \
  }

#define COMPUTE(QQ)                                                            \
  {                                                                            \
    const char* xsb = smem + ((QQ) & 3) * BUFSZ;                               \
    _Pragma("unroll") for (int khkw = 0; khkw < 4; ++khkw) {                   \
      v8bf b[4];                                                               \
      _Pragma("unroll") for (int r = 0; r < 2; ++r)                            \
        _Pragma("unroll") for (int hh = 0; hh < 2; ++hh)                       \
          b[r * 2 + hh] =                                                      \
              *(const v8bf*)(xsb + boff[khkw] + r * 8448 + hh * 2048);         \
      __builtin_amdgcn_s_setprio(1);                                           \
      _Pragma("unroll") for (int m = 0; m < 2; ++m)                            \
        _Pragma("unroll") for (int f = 0; f < 4; ++f)                          \
          acc[m][f] = __builtin_amdgcn_mfma_f32_16x16x32_bf16(                 \
              a_reg[khkw][m], b[f], acc[m][f], 0, 0, 0);                       \
      __builtin_amdgcn_s_setprio(0);                                           \
    }                                                                          \
  }

  // prologue: L0,L1,L2 in flight together (one delivery round-trip);
  // W0 waits only L0 (L1,L2 stay); L3 reuses b0 after W0 consumed it.
  LOADQ(0, xlo0, xhi0);
  LOADQ(1, xlo1, xhi1);
  LOADQ(2, xlo2, xhi2);
  WRITEQ(0, xlo0, xhi0);
  LOADQ(3, xlo0, xhi0);
  WRITEQ(1, xlo1, xhi1);
  __syncthreads();

  // loop: slot q = { A(q); L(q+4) -> bank freed at slot q-1; W(q+2); C(q) }
  // barriers after odd slots. Banks: W2<-b2, W3<-b0, W4<-b1, W5<-b2,
  // W6<-b0, W7<-b1; L4->b1, L5->b2, L6->b0, L7->b1.
  A_LOAD(0); LOADQ(4, xlo1, xhi1); WRITEQ(2, xlo2, xhi2); COMPUTE(0);
  A_LOAD(1); LOADQ(5, xlo2, xhi2); WRITEQ(3, xlo0, xhi0); COMPUTE(1);
  __syncthreads();
  A_LOAD(2); LOADQ(6, xlo0, xhi0); WRITEQ(4, xlo1, xhi1); COMPUTE(2);
  A_LOAD(3); LOADQ(7, xlo1, xhi1); WRITEQ(5, xlo2, xhi2); COMPUTE(3);
  __syncthreads();
  A_LOAD(4); WRITEQ(6, xlo0, xhi0); COMPUTE(4);
  A_LOAD(5); WRITEQ(7, xlo1, xhi1); COMPUTE(5);
  __syncthreads();
  A_LOAD(6); COMPUTE(6);
  A_LOAD(7); COMPUTE(7);

  // ---- epilogue: 2 passes, row-pair per pass, all waves active ----
  // acc D layout: col=lane&15 (pixel), row=(lane>>4)*4+reg (oc).
  // eb layout: [rr=ph(2)][oc(128)][68] f32 = 69632 B.
  float bv[2][4];
#pragma unroll
  for (int m = 0; m < 2; ++m)
#pragma unroll
    for (int reg = 0; reg < 4; ++reg)
      bv[m][reg] = bias[(ocg * 32 + m * 16 + lg * 4 + reg) * 4 + kp];

  float* eb = (float*)smem;
#pragma unroll
  for (int p = 0; p < 2; ++p) {
    __syncthreads();                 // loop reads / prev pass reads done
    // every wave writes its r=p fragments into row rr=ph
    {
#pragma unroll
      for (int m = 0; m < 2; ++m)
#pragma unroll
        for (int hh = 0; hh < 2; ++hh) {
          f32x4 v = acc[m][p * 2 + hh];
          int w = 2 * (hh * 16 + lcol) + pw;       // <= 63
#pragma unroll
          for (int reg = 0; reg < 4; ++reg)
            eb[((ph << 7) + ocg * 32 + m * 16 + lg * 4 + reg) * 68 + w] =
                v[reg] + bv[m][reg];
        }
    }
    __syncthreads();                 // tile complete
#pragma unroll
    for (int s = 0; s < 4; ++s) {
      int rowid = (tid >> 4) + (s << 6);           // 0..255 = rr*128 + oc
      int rr = rowid >> 7, oc = rowid & 127;
      int h = h0 + 2 * p + rr;
      if (h < OHW) {
        const float* erow = eb + rowid * 68;
        float* orow = out + ((size_t)(n * NOC + oc) * OHW + h) * OHW;
        const int lc2 = tid & 15;
#pragma unroll
        for (int b = 0; b < 4; ++b) {
          int w = lc2 + 16 * b;
          if (w < OHW) orow[w] = erow[w];
        }
      }
    }
  }
#undef A_LOAD
#undef LOADQ
#undef WRITEQ
#undef COMPUTE
}

extern "C" void kernel_launch(void* const* d_in, const int* in_sizes, int n_in,
                              void* d_out, int out_size, void* d_ws, size_t ws_size,
                              hipStream_t stream) {
  const float* x      = (const float*)d_in[0];
  const float* weight = (const float*)d_in[1];
  const float* bias   = (const float*)d_in[2];
  float* out          = (float*)d_out;
  __bf16* Wf          = (__bf16*)d_ws;   // 1 MiB fragment-ordered weights

  wprep<<<512, 256, 0, stream>>>(weight, Wf);
  robin_main<<<256, 1024, 0, stream>>>(x, Wf, bias, out);
}